// Round 1
// baseline (267.093 us; speedup 1.0000x reference)
//
#include <hip/hip_runtime.h>

typedef __bf16 bf16_t;
typedef __bf16 bf16x4 __attribute__((ext_vector_type(4)));
typedef __bf16 bf16x8 __attribute__((ext_vector_type(8)));
typedef float f32x4 __attribute__((ext_vector_type(4)));

#define NB 4        // batch
#define SS 2048     // seq
#define DM 1024     // d_model
#define NH 16       // heads
#define DK 64       // d_kv
#define MM (NB*SS)  // 8192 rows
#define LOG2E 1.44269504f

// ---------------- fused prep: convert H, transpose weights, bias table ----------------
// blocks [0,8192): H fp32 -> bf16 (float4/lane)
// blocks [8192,9216): 64x64 transpose-convert tiles of the 4 weight matrices
// blocks [9216,9232): T5 bias table biasT[h][rel+2047], pre-scaled by log2(e)
__global__ __launch_bounds__(256) void k_prep(
    const float* __restrict__ H, bf16_t* __restrict__ Hbf,
    const float* __restrict__ W0, const float* __restrict__ W1,
    const float* __restrict__ W2, const float* __restrict__ W3,
    bf16_t* __restrict__ T0, bf16_t* __restrict__ T1,
    bf16_t* __restrict__ T2, bf16_t* __restrict__ T3,
    const float* __restrict__ rel_emb, float* __restrict__ biasT) {
  __shared__ float t[64][65];
  const int blk = blockIdx.x, tid = threadIdx.x;
  if (blk < 8192) {
    int i = blk * 256 + tid;
    float4 v = ((const float4*)H)[i];
    bf16x4 o = {(bf16_t)v.x, (bf16_t)v.y, (bf16_t)v.z, (bf16_t)v.w};
    *(bf16x4*)(Hbf + 4 * (size_t)i) = o;
  } else if (blk < 9216) {
    int tt = blk - 8192;
    int which = tt >> 8, rem = tt & 255;
    int k0 = (rem >> 4) * 64, n0 = (rem & 15) * 64;
    const float* W = which == 0 ? W0 : which == 1 ? W1 : which == 2 ? W2 : W3;
    bf16_t* T = which == 0 ? T0 : which == 1 ? T1 : which == 2 ? T2 : T3;
#pragma unroll
    for (int i = 0; i < 16; i++) {
      int idx = tid + i * 256; int r = idx >> 6, c = idx & 63;
      t[r][c] = W[(size_t)(k0 + r) * DM + n0 + c];
    }
    __syncthreads();
#pragma unroll
    for (int i = 0; i < 16; i++) {
      int idx = tid + i * 256; int r = idx >> 6, c = idx & 63;
      T[(size_t)(n0 + r) * DM + k0 + c] = (bf16_t)t[c][r];
    }
  } else {
    int tt = (blk - 9216) * 256 + tid;
    if (tt < 2 * SS - 1) {
      int rel = tt - (SS - 1);     // rel = j - i
      int n = -rel;
      int ret = 0;
      if (n < 0) { ret = 16; n = -n; }
      int bucket;
      if (n < 8) bucket = n;
      else {
        int v = 8 + (int)(logf((float)n * 0.125f) * (8.0f / logf(16.0f)));
        bucket = v < 15 ? v : 15;
      }
      bucket += ret;
#pragma unroll
      for (int h = 0; h < NH; h++)
        biasT[h * (2 * SS - 1) + tt] = rel_emb[bucket * NH + h] * LOG2E;
    }
  }
}

// ---------------- async 16B global -> LDS (lane i deposits at lds_base + 16*i) -------------
__device__ __forceinline__ void gld16(const bf16_t* g, bf16_t* l) {
  __builtin_amdgcn_global_load_lds(
      (const __attribute__((address_space(1))) unsigned int*)g,
      (__attribute__((address_space(3))) unsigned int*)l, 16, 0, 0);
}

// ---------------- m97-style GEMM mainloop: C[128x128] = A[MxK] * Bt[NxK]^T ----------------
__device__ __forceinline__ void gemm_tile(const bf16_t* __restrict__ A,
                                          const bf16_t* __restrict__ Bt, const int K,
                                          const int m0, const int n0,
                                          bf16_t* As, bf16_t* Bs, f32x4 (&acc)[4][4]) {
  const int tid = threadIdx.x;
  const int lane = tid & 63, wave = tid >> 6;
  const int l15 = lane & 15, quad = lane >> 4;
  const int wm = (wave >> 1) * 64, wn = (wave & 1) * 64;
  const int wwu = __builtin_amdgcn_readfirstlane(wave);
  const f32x4 z4 = {0.f, 0.f, 0.f, 0.f};
#pragma unroll
  for (int i = 0; i < 4; i++)
#pragma unroll
    for (int j = 0; j < 4; j++) acc[i][j] = z4;

  const int rr = lane >> 2;
  const int cc = (lane & 3) * 8;
  for (int k0 = 0; k0 < K; k0 += 32) {
    __syncthreads();
    gld16(A + (size_t)(m0 + wwu * 32 + rr) * K + k0 + cc,       As + wwu * 1024);
    gld16(A + (size_t)(m0 + wwu * 32 + 16 + rr) * K + k0 + cc,  As + wwu * 1024 + 512);
    gld16(Bt + (size_t)(n0 + wwu * 32 + rr) * K + k0 + cc,      Bs + wwu * 1024);
    gld16(Bt + (size_t)(n0 + wwu * 32 + 16 + rr) * K + k0 + cc, Bs + wwu * 1024 + 512);
    __syncthreads();
    bf16x8 af[4], bfr[4];
#pragma unroll
    for (int i = 0; i < 4; i++) {
      af[i]  = *(const bf16x8*)(As + (wm + i * 16 + l15) * 32 + quad * 8);
      bfr[i] = *(const bf16x8*)(Bs + (wn + i * 16 + l15) * 32 + quad * 8);
    }
#pragma unroll
    for (int i = 0; i < 4; i++)
#pragma unroll
      for (int j = 0; j < 4; j++)
        acc[i][j] = __builtin_amdgcn_mfma_f32_16x16x32_bf16(af[i], bfr[j], acc[i][j], 0, 0, 0);
  }
}

// ---------------- QKV projection ----------------
// Grid: (m-panel FASTEST, n-panel, which) -> XCD d keeps A-slice (m%8==d) L2-resident
// across all (n,which) phases; only B (6.3MB) is multicast across XCDs.
// Q: row-major [bh][s][d], scaled by log2e.
// K, V: FRAGMENT-MAJOR: [bh][T=s/64][slot 0..7][lane 0..63][j 0..7] (slot = 1KB), exactly
// the MFMA fragments k_attn consumes -> attention reads lane-linear 16B/lane.
__global__ __launch_bounds__(256) void k_gemm_qkv(
    const bf16_t* __restrict__ A, const bf16_t* __restrict__ Wqt,
    const bf16_t* __restrict__ Wkt, const bf16_t* __restrict__ Wvt,
    bf16_t* __restrict__ Q, bf16_t* __restrict__ Kf, bf16_t* __restrict__ Vf) {
  __shared__ bf16_t As[128 * 32];
  __shared__ bf16_t Bs[128 * 32];
  const int which = blockIdx.z;
  const bf16_t* Bt = which == 0 ? Wqt : (which == 1 ? Wkt : Wvt);
  const int m0 = blockIdx.x * 128, n0 = blockIdx.y * 128;
  f32x4 acc[4][4];
  gemm_tile(A, Bt, DM, m0, n0, As, Bs, acc);

  const int tid = threadIdx.x;
  const int lane = tid & 63, wave = tid >> 6;
  const int l15 = lane & 15, quad = lane >> 4;
  const int wm = (wave >> 1) * 64, wn = (wave & 1) * 64;

  if (which == 0) {
#pragma unroll
    for (int i = 0; i < 4; i++)
#pragma unroll
      for (int j = 0; j < 4; j++)
#pragma unroll
        for (int r = 0; r < 4; r++) {
          int m = m0 + wm + i * 16 + quad * 4 + r;
          int n = n0 + wn + j * 16 + l15;
          int b = m >> 11, s = m & (SS - 1);
          int h = n >> 6, d = n & 63;
          Q[(((size_t)(b * NH + h)) * SS + s) * DK + d] = (bf16_t)(acc[i][j][r] * LOG2E);
        }
  } else if (which == 1) {
#pragma unroll
    for (int i = 0; i < 4; i++)
#pragma unroll
      for (int j = 0; j < 4; j++)
#pragma unroll
        for (int r = 0; r < 4; r++) {
          int m = m0 + wm + i * 16 + quad * 4 + r;
          int n = n0 + wn + j * 16 + l15;
          int b = m >> 11, s = m & (SS - 1);
          int h = n >> 6, d = n & 63;
          int slot = 4 * ((s >> 5) & 1) + 2 * ((s >> 2) & 1) + (d >> 5);
          int fl = ((d >> 3) & 3) * 16 + 4 * ((s >> 3) & 3) + (s & 3);
          Kf[(((size_t)(b * NH + h) * 32 + (s >> 6)) * 8 + slot) * 512 + fl * 8 + (d & 7)] =
              (bf16_t)acc[i][j][r];
        }
  } else {
#pragma unroll
    for (int i = 0; i < 4; i++)
#pragma unroll
      for (int j = 0; j < 4; j++) {
        int m = m0 + wm + i * 16 + quad * 4;   // 4 consecutive s, 4-aligned
        int n = n0 + wn + j * 16 + l15;
        int b = m >> 11, s = m & (SS - 1);
        int h = n >> 6, d = n & 63;
        int slot = 4 * ((s >> 5) & 1) + (d >> 4);
        int fl = ((s >> 3) & 3) * 16 + (d & 15);
        bf16x4 pk = {(bf16_t)acc[i][j][0], (bf16_t)acc[i][j][1],
                     (bf16_t)acc[i][j][2], (bf16_t)acc[i][j][3]};
        *(bf16x4*)(&Vf[(((size_t)(b * NH + h) * 32 + (s >> 6)) * 8 + slot) * 512 +
                       fl * 8 + (s & 7)]) = pk;
      }
  }
}

// ---------------- flash attention v2: q-split waves + LDS-staged K/V ---------------
// Each of the 4 waves owns 32 q-rows and walks ALL 64 keys of every tile:
//  - accO halves to [2][4] (32 regs) + accS 8 -> ~150 regs total -> 3 blocks/CU
//    (was 188 -> 2 blocks/CU), __launch_bounds__(256,3).
//  - accS now holds the FULL softmax denominator per lane: the 32KB Ored buffer,
//    OsumS, and the cross-wave reduction epilogue are gone.
//  - K/V fragment tiles (8KB each) are staged global->LDS ONCE per block via
//    global_load_lds (double-buffered, 32KB) instead of each kh-wave re-reading
//    them from L2: block L2 read traffic 1MB -> 0.53MB.
//  - one __syncthreads per tile; its implicit vmcnt(0) waits on loads issued a
//    full body (~500cy) earlier, so prefetch survives the drain.
//  - bijective XCD swizzle: XCD d owns bh in [8d, 8d+8) -> its K/V slice is 4MB,
//    exactly one L2; staging loads become L2 hits after first touch.
__global__ __launch_bounds__(256, 3) void k_attn(const bf16_t* __restrict__ Qg,
                                                 const bf16_t* __restrict__ Kf,
                                                 const bf16_t* __restrict__ Vf,
                                                 const float* __restrict__ biasT,
                                                 bf16_t* __restrict__ ctx) {
  const int lin = blockIdx.x + 16 * blockIdx.y;      // 1024 blocks, x fastest
  const int nid = (lin & 7) * 128 + (lin >> 3);      // bijective XCD chunking
  const int bh = nid >> 4;
  const int it0 = (nid & 15) * 128;
  const int b = bh >> 4, h = bh & 15;
  const bf16_t* Qp = Qg + ((size_t)bh * SS + it0) * DK;
  const float* biasH = biasT + h * (2 * SS - 1);

  __shared__ float bias2[512][2];      // diag-band: bias2[w] = {B(w-256), B(w-255)}
  __shared__ bf16_t lK[2][4096];       // double-buffered K fragment tile (8KB each)
  __shared__ bf16_t lV[2][4096];       // double-buffered V fragment tile

  const int tid = threadIdx.x;
  const int lane = tid & 63, wave = tid >> 6;
  const int l15 = lane & 15, quad = lane >> 4;
  const int wvu = __builtin_amdgcn_readfirstlane(wave);

  for (int w = tid; w < 512; w += 256) {
    int g = w - 256 + (SS - 1);
    bias2[w][0] = biasH[g];
    bias2[w][1] = biasH[g + 1];
  }
  const float Bpos = biasH[(SS - 1) + 1024];   // rel >= 128: saturated bucket 31
  const float Bneg = biasH[(SS - 1) - 1024];   // rel <= -128: saturated bucket 15

  const bf16_t* KfB = Kf + (size_t)bh * 32 * 4096;
  const bf16_t* VfB = Vf + (size_t)bh * 32 * 4096;
  const int so = wvu * 1024 + lane * 8;        // this lane's 16B within the wave's 2KB share
  auto stage = [&](int it, int bufi) {
    const bf16_t* kg = KfB + (size_t)it * 4096 + so;
    const bf16_t* vg = VfB + (size_t)it * 4096 + so;
    gld16(kg,       lK[bufi] + wvu * 1024);
    gld16(kg + 512, lK[bufi] + wvu * 1024 + 512);
    gld16(vg,       lV[bufi] + wvu * 1024);
    gld16(vg + 512, lV[bufi] + wvu * 1024 + 512);
  };

  bf16x8 qf[2][2];
#pragma unroll
  for (int mi = 0; mi < 2; mi++) {
    const bf16_t* qr = Qp + (size_t)(32 * wave + mi * 16 + l15) * DK + quad * 8;
    qf[mi][0] = *(const bf16x8*)qr;
    qf[mi][1] = *(const bf16x8*)(qr + 32);
  }

  f32x4 accO[2][4], accS[2];
  const f32x4 z4 = {0.f, 0.f, 0.f, 0.f};
#pragma unroll
  for (int mi = 0; mi < 2; mi++) {
    accS[mi] = z4;
#pragma unroll
    for (int ni = 0; ni < 4; ni++) accO[mi][ni] = z4;
  }
  const bf16_t one = (bf16_t)1.0f;
  const bf16x8 ones = {one, one, one, one, one, one, one, one};

  const int wb0 = 8 * quad - 32 * wave - l15 - it0 + 256;

  stage(0, 0);

  for (int it = 0; it < 32; ++it) {
    const int buf = it & 1;
    __syncthreads();                           // lK/lV[buf] ready (drains vmcnt)
    if (it + 1 < 32) stage(it + 1, buf ^ 1);   // prefetch next tile into other buffer

    const int diff = it * 64 - it0;
    const bool band = (diff >= -128) && (diff < 256);
    const float cconst = diff >= 256 ? Bpos : Bneg;
    const f32x4 csplat = {cconst, cconst, cconst, cconst};

    bf16x8 kfr[4][2], vfr[8];
#pragma unroll
    for (int kt = 0; kt < 4; kt++)
#pragma unroll
      for (int hf = 0; hf < 2; hf++)
        kfr[kt][hf] = *(const bf16x8*)(lK[buf] + (kt * 2 + hf) * 512 + lane * 8);
#pragma unroll
    for (int sl = 0; sl < 8; sl++)
      vfr[sl] = *(const bf16x8*)(lV[buf] + sl * 512 + lane * 8);

#pragma unroll
    for (int mi = 0; mi < 2; mi++)
#pragma unroll
      for (int k2 = 0; k2 < 2; k2++) {
        f32x4 c0, c1;
        if (band) {
          const int w = it * 64 + 32 * k2 + wb0 - mi * 16;
          float2 a0 = *(const float2*)bias2[w],     b0 = *(const float2*)bias2[w + 2];
          float2 a1 = *(const float2*)bias2[w + 4], b1 = *(const float2*)bias2[w + 6];
          c0 = f32x4{a0.x, a0.y, b0.x, b0.y};
          c1 = f32x4{a1.x, a1.y, b1.x, b1.y};
        } else {
          c0 = csplat;
          c1 = csplat;
        }
        f32x4 s0 = __builtin_amdgcn_mfma_f32_16x16x32_bf16(
            kfr[2 * k2][1], qf[mi][1],
            __builtin_amdgcn_mfma_f32_16x16x32_bf16(kfr[2 * k2][0], qf[mi][0], c0, 0, 0, 0),
            0, 0, 0);
        f32x4 s1 = __builtin_amdgcn_mfma_f32_16x16x32_bf16(
            kfr[2 * k2 + 1][1], qf[mi][1],
            __builtin_amdgcn_mfma_f32_16x16x32_bf16(kfr[2 * k2 + 1][0], qf[mi][0], c1, 0, 0, 0),
            0, 0, 0);
        bf16x8 pf = {(bf16_t)__builtin_amdgcn_exp2f(s0[0]), (bf16_t)__builtin_amdgcn_exp2f(s0[1]),
                     (bf16_t)__builtin_amdgcn_exp2f(s0[2]), (bf16_t)__builtin_amdgcn_exp2f(s0[3]),
                     (bf16_t)__builtin_amdgcn_exp2f(s1[0]), (bf16_t)__builtin_amdgcn_exp2f(s1[1]),
                     (bf16_t)__builtin_amdgcn_exp2f(s1[2]), (bf16_t)__builtin_amdgcn_exp2f(s1[3])};
#pragma unroll
        for (int ni = 0; ni < 4; ni++)
          accO[mi][ni] = __builtin_amdgcn_mfma_f32_16x16x32_bf16(vfr[k2 * 4 + ni], pf,
                                                                 accO[mi][ni], 0, 0, 0);
        accS[mi] = __builtin_amdgcn_mfma_f32_16x16x32_bf16(ones, pf, accS[mi], 0, 0, 0);
      }
  }

  // epilogue: every lane already holds its full denominator -> direct store
#pragma unroll
  for (int mi = 0; mi < 2; mi++) {
    float inv = 1.0f / accS[mi][0];
    int srow = it0 + 32 * wave + mi * 16 + l15;
#pragma unroll
    for (int ni = 0; ni < 4; ni++) {
      f32x4 o = accO[mi][ni];
      bf16x4 pk = {(bf16_t)(o[0] * inv), (bf16_t)(o[1] * inv),
                   (bf16_t)(o[2] * inv), (bf16_t)(o[3] * inv)};
      *(bf16x4*)(&ctx[((size_t)(b * SS + srow)) * DM + h * DK + ni * 16 + quad * 4]) = pk;
    }
  }
}

// ---------------- output projection: out = ctx @ Wo (fp32 out), m-panel-fastest grid ------
__global__ __launch_bounds__(256) void k_gemm_out(const bf16_t* __restrict__ A,
                                                  const bf16_t* __restrict__ Wot,
                                                  float* __restrict__ out) {
  __shared__ bf16_t As[128 * 32];
  __shared__ bf16_t Bs[128 * 32];
  const int m0 = blockIdx.x * 128, n0 = blockIdx.y * 128;
  f32x4 acc[4][4];
  gemm_tile(A, Wot, DM, m0, n0, As, Bs, acc);

  const int tid = threadIdx.x;
  const int lane = tid & 63, wave = tid >> 6;
  const int l15 = lane & 15, quad = lane >> 4;
  const int wm = (wave >> 1) * 64, wn = (wave & 1) * 64;
#pragma unroll
  for (int i = 0; i < 4; i++)
#pragma unroll
    for (int j = 0; j < 4; j++)
#pragma unroll
      for (int r = 0; r < 4; r++) {
        int m = m0 + wm + i * 16 + quad * 4 + r;
        int n = n0 + wn + j * 16 + l15;
        out[(size_t)m * DM + n] = acc[i][j][r];
      }
}

extern "C" void kernel_launch(void* const* d_in, const int* in_sizes, int n_in,
                              void* d_out, int out_size, void* d_ws, size_t ws_size,
                              hipStream_t stream) {
  (void)in_sizes; (void)n_in; (void)out_size; (void)ws_size;
  const float* H  = (const float*)d_in[0];
  const float* Wq = (const float*)d_in[1];
  const float* Wk = (const float*)d_in[2];
  const float* Wv = (const float*)d_in[3];
  const float* Wo = (const float*)d_in[4];
  const float* rel = (const float*)d_in[5];
  float* out = (float*)d_out;

  char* w = (char*)d_ws;
  bf16_t* Hbf = (bf16_t*)w; w += (size_t)MM * DM * 2;
  bf16_t* Wqt = (bf16_t*)w; w += (size_t)DM * DM * 2;
  bf16_t* Wkt = (bf16_t*)w; w += (size_t)DM * DM * 2;
  bf16_t* Wvt = (bf16_t*)w; w += (size_t)DM * DM * 2;
  bf16_t* Wot = (bf16_t*)w; w += (size_t)DM * DM * 2;
  bf16_t* Q   = (bf16_t*)w; w += (size_t)MM * DM * 2;
  bf16_t* Kf  = (bf16_t*)w; w += (size_t)MM * DM * 2;
  bf16_t* Vf  = (bf16_t*)w; w += (size_t)MM * DM * 2;
  bf16_t* CTX = (bf16_t*)w; w += (size_t)MM * DM * 2;
  float* biasT = (float*)w;  // NH * 4095 floats

  k_prep<<<9232, 256, 0, stream>>>(H, Hbf, Wq, Wk, Wv, Wo, Wqt, Wkt, Wvt, Wot, rel, biasT);
  k_gemm_qkv<<<dim3(MM / 128, DM / 128, 3), 256, 0, stream>>>(Hbf, Wqt, Wkt, Wvt, Q, Kf, Vf);
  k_attn<<<dim3(SS / 128, NB * NH), 256, 0, stream>>>(Q, Kf, Vf, biasT, CTX);
  k_gemm_out<<<dim3(MM / 128, DM / 128), 256, 0, stream>>>(CTX, Wot, out);
}

// Round 2
// 266.350 us; speedup vs baseline: 1.0028x; 1.0028x over previous
//
#include <hip/hip_runtime.h>

typedef __bf16 bf16_t;
typedef __bf16 bf16x4 __attribute__((ext_vector_type(4)));
typedef __bf16 bf16x8 __attribute__((ext_vector_type(8)));
typedef float f32x4 __attribute__((ext_vector_type(4)));

#define NB 4        // batch
#define SS 2048     // seq
#define DM 1024     // d_model
#define NH 16       // heads
#define DK 64       // d_kv
#define MM (NB*SS)  // 8192 rows
#define LOG2E 1.44269504f

// ---------------- fused prep: convert H, transpose weights, bias table ----------------
__global__ __launch_bounds__(256) void k_prep(
    const float* __restrict__ H, bf16_t* __restrict__ Hbf,
    const float* __restrict__ W0, const float* __restrict__ W1,
    const float* __restrict__ W2, const float* __restrict__ W3,
    bf16_t* __restrict__ T0, bf16_t* __restrict__ T1,
    bf16_t* __restrict__ T2, bf16_t* __restrict__ T3,
    const float* __restrict__ rel_emb, float* __restrict__ biasT) {
  __shared__ float t[64][65];
  const int blk = blockIdx.x, tid = threadIdx.x;
  if (blk < 8192) {
    int i = blk * 256 + tid;
    float4 v = ((const float4*)H)[i];
    bf16x4 o = {(bf16_t)v.x, (bf16_t)v.y, (bf16_t)v.z, (bf16_t)v.w};
    *(bf16x4*)(Hbf + 4 * (size_t)i) = o;
  } else if (blk < 9216) {
    int tt = blk - 8192;
    int which = tt >> 8, rem = tt & 255;
    int k0 = (rem >> 4) * 64, n0 = (rem & 15) * 64;
    const float* W = which == 0 ? W0 : which == 1 ? W1 : which == 2 ? W2 : W3;
    bf16_t* T = which == 0 ? T0 : which == 1 ? T1 : which == 2 ? T2 : T3;
#pragma unroll
    for (int i = 0; i < 16; i++) {
      int idx = tid + i * 256; int r = idx >> 6, c = idx & 63;
      t[r][c] = W[(size_t)(k0 + r) * DM + n0 + c];
    }
    __syncthreads();
#pragma unroll
    for (int i = 0; i < 16; i++) {
      int idx = tid + i * 256; int r = idx >> 6, c = idx & 63;
      T[(size_t)(n0 + r) * DM + k0 + c] = (bf16_t)t[c][r];
    }
  } else {
    int tt = (blk - 9216) * 256 + tid;
    if (tt < 2 * SS - 1) {
      int rel = tt - (SS - 1);     // rel = j - i
      int n = -rel;
      int ret = 0;
      if (n < 0) { ret = 16; n = -n; }
      int bucket;
      if (n < 8) bucket = n;
      else {
        int v = 8 + (int)(logf((float)n * 0.125f) * (8.0f / logf(16.0f)));
        bucket = v < 15 ? v : 15;
      }
      bucket += ret;
#pragma unroll
      for (int h = 0; h < NH; h++)
        biasT[h * (2 * SS - 1) + tt] = rel_emb[bucket * NH + h] * LOG2E;
    }
  }
}

// ---------------- async 16B global -> LDS (lane i deposits at lds_base + 16*i) -------------
__device__ __forceinline__ void gld16(const bf16_t* g, bf16_t* l) {
  __builtin_amdgcn_global_load_lds(
      (const __attribute__((address_space(1))) unsigned int*)g,
      (__attribute__((address_space(3))) unsigned int*)l, 16, 0, 0);
}

// ---------------- m97-style GEMM mainloop: C[128x128] = A[MxK] * Bt[NxK]^T ----------------
__device__ __forceinline__ void gemm_tile(const bf16_t* __restrict__ A,
                                          const bf16_t* __restrict__ Bt, const int K,
                                          const int m0, const int n0,
                                          bf16_t* As, bf16_t* Bs, f32x4 (&acc)[4][4]) {
  const int tid = threadIdx.x;
  const int lane = tid & 63, wave = tid >> 6;
  const int l15 = lane & 15, quad = lane >> 4;
  const int wm = (wave >> 1) * 64, wn = (wave & 1) * 64;
  const int wwu = __builtin_amdgcn_readfirstlane(wave);
  const f32x4 z4 = {0.f, 0.f, 0.f, 0.f};
#pragma unroll
  for (int i = 0; i < 4; i++)
#pragma unroll
    for (int j = 0; j < 4; j++) acc[i][j] = z4;

  const int rr = lane >> 2;
  const int cc = (lane & 3) * 8;
  for (int k0 = 0; k0 < K; k0 += 32) {
    __syncthreads();
    gld16(A + (size_t)(m0 + wwu * 32 + rr) * K + k0 + cc,       As + wwu * 1024);
    gld16(A + (size_t)(m0 + wwu * 32 + 16 + rr) * K + k0 + cc,  As + wwu * 1024 + 512);
    gld16(Bt + (size_t)(n0 + wwu * 32 + rr) * K + k0 + cc,      Bs + wwu * 1024);
    gld16(Bt + (size_t)(n0 + wwu * 32 + 16 + rr) * K + k0 + cc, Bs + wwu * 1024 + 512);
    __syncthreads();
    bf16x8 af[4], bfr[4];
#pragma unroll
    for (int i = 0; i < 4; i++) {
      af[i]  = *(const bf16x8*)(As + (wm + i * 16 + l15) * 32 + quad * 8);
      bfr[i] = *(const bf16x8*)(Bs + (wn + i * 16 + l15) * 32 + quad * 8);
    }
#pragma unroll
    for (int i = 0; i < 4; i++)
#pragma unroll
      for (int j = 0; j < 4; j++)
        acc[i][j] = __builtin_amdgcn_mfma_f32_16x16x32_bf16(af[i], bfr[j], acc[i][j], 0, 0, 0);
  }
}

// ---------------- QKV projection (unchanged) ----------------
__global__ __launch_bounds__(256) void k_gemm_qkv(
    const bf16_t* __restrict__ A, const bf16_t* __restrict__ Wqt,
    const bf16_t* __restrict__ Wkt, const bf16_t* __restrict__ Wvt,
    bf16_t* __restrict__ Q, bf16_t* __restrict__ Kf, bf16_t* __restrict__ Vf) {
  __shared__ bf16_t As[128 * 32];
  __shared__ bf16_t Bs[128 * 32];
  const int which = blockIdx.z;
  const bf16_t* Bt = which == 0 ? Wqt : (which == 1 ? Wkt : Wvt);
  const int m0 = blockIdx.x * 128, n0 = blockIdx.y * 128;
  f32x4 acc[4][4];
  gemm_tile(A, Bt, DM, m0, n0, As, Bs, acc);

  const int tid = threadIdx.x;
  const int lane = tid & 63, wave = tid >> 6;
  const int l15 = lane & 15, quad = lane >> 4;
  const int wm = (wave >> 1) * 64, wn = (wave & 1) * 64;

  if (which == 0) {
#pragma unroll
    for (int i = 0; i < 4; i++)
#pragma unroll
      for (int j = 0; j < 4; j++)
#pragma unroll
        for (int r = 0; r < 4; r++) {
          int m = m0 + wm + i * 16 + quad * 4 + r;
          int n = n0 + wn + j * 16 + l15;
          int b = m >> 11, s = m & (SS - 1);
          int h = n >> 6, d = n & 63;
          Q[(((size_t)(b * NH + h)) * SS + s) * DK + d] = (bf16_t)(acc[i][j][r] * LOG2E);
        }
  } else if (which == 1) {
#pragma unroll
    for (int i = 0; i < 4; i++)
#pragma unroll
      for (int j = 0; j < 4; j++)
#pragma unroll
        for (int r = 0; r < 4; r++) {
          int m = m0 + wm + i * 16 + quad * 4 + r;
          int n = n0 + wn + j * 16 + l15;
          int b = m >> 11, s = m & (SS - 1);
          int h = n >> 6, d = n & 63;
          int slot = 4 * ((s >> 5) & 1) + 2 * ((s >> 2) & 1) + (d >> 5);
          int fl = ((d >> 3) & 3) * 16 + 4 * ((s >> 3) & 3) + (s & 3);
          Kf[(((size_t)(b * NH + h) * 32 + (s >> 6)) * 8 + slot) * 512 + fl * 8 + (d & 7)] =
              (bf16_t)acc[i][j][r];
        }
  } else {
#pragma unroll
    for (int i = 0; i < 4; i++)
#pragma unroll
      for (int j = 0; j < 4; j++) {
        int m = m0 + wm + i * 16 + quad * 4;   // 4 consecutive s, 4-aligned
        int n = n0 + wn + j * 16 + l15;
        int b = m >> 11, s = m & (SS - 1);
        int h = n >> 6, d = n & 63;
        int slot = 4 * ((s >> 5) & 1) + (d >> 4);
        int fl = ((s >> 3) & 3) * 16 + (d & 15);
        bf16x4 pk = {(bf16_t)acc[i][j][0], (bf16_t)acc[i][j][1],
                     (bf16_t)acc[i][j][2], (bf16_t)acc[i][j][3]};
        *(bf16x4*)(&Vf[(((size_t)(b * NH + h) * 32 + (s >> 6)) * 8 + slot) * 512 +
                       fl * 8 + (s & 7)]) = pk;
      }
  }
}

// ---------------- flash attention v3: R0 structure + XCD swizzle + single-buffer K/V ------
// Post-mortem R1: kernel is latency/phase-bound, not BW-bound. Barriers in the main loop
// forced waves into the same phase (VALU and MFMA peaks alternate instead of overlap) and
// the LDS round-trip added pipe traffic -> 91us. Revert to R0's barrier-free global-direct
// loop (86.6us proven), plus:
//  - bijective XCD swizzle (kept from R1): each XCD owns 8 bh -> 4MB K/V slice L2-resident,
//    fragment loads become ~200cy L2 hits instead of ~900cy HBM misses (R0 FETCH 140MB).
//  - SINGLE-buffered K/V fragments, loaded right after consumption: -32 VGPR -> ~156 total
//    -> 3 waves/SIMD (was 2). The load bubble at body start is covered by the other two
//    waves on the SIMD, which drift into anti-phase (no barriers).
__global__ __launch_bounds__(256, 3) void k_attn(const bf16_t* __restrict__ Qg,
                                                 const bf16_t* __restrict__ Kf,
                                                 const bf16_t* __restrict__ Vf,
                                                 const float* __restrict__ biasT,
                                                 bf16_t* __restrict__ ctx) {
  const int lin = blockIdx.x + 16 * blockIdx.y;      // 1024 blocks, x fastest
  const int nid = (lin & 7) * 128 + (lin >> 3);      // bijective XCD chunking
  const int bh = nid >> 4;
  const int it0 = (nid & 15) * 128;
  const int b = bh >> 4, h = bh & 15;
  const bf16_t* Qp = Qg + ((size_t)bh * SS + it0) * DK;
  const float* biasH = biasT + h * (2 * SS - 1);

  __shared__ float bias2[512][2];         // diag-band: bias2[w] = {B(w-256), B(w-255)}
  __shared__ float OsumS[2][4][16];       // per (qh, mi, qrow) partial denominators
  __shared__ f32x4 Ored[2 * 4 * 4 * 64];  // 32 KB cross-wave O partials

  const int tid = threadIdx.x;
  const int lane = tid & 63, wave = tid >> 6;
  const int l15 = lane & 15, quad = lane >> 4;
  const int kh = wave & 1, qh = wave >> 1;

  for (int w = tid; w < 512; w += 256) {
    int g = w - 256 + (SS - 1);
    bias2[w][0] = biasH[g];
    bias2[w][1] = biasH[g + 1];
  }
  const float Bpos = biasH[(SS - 1) + 1024];   // rel >= 128: saturated bucket 31
  const float Bneg = biasH[(SS - 1) - 1024];   // rel <= -128: saturated bucket 15

  const bf16_t* KfB = Kf + (size_t)bh * 32 * 4096 + lane * 8;
  const bf16_t* VfB = Vf + (size_t)bh * 32 * 4096 + lane * 8;
  auto loadfrag = [&](int it, bf16x8 (&kf)[2][2], bf16x8 (&vf)[4]) {
    const bf16_t* kb = KfB + (size_t)it * 4096;
#pragma unroll
    for (int t = 0; t < 2; t++)
#pragma unroll
      for (int hf = 0; hf < 2; hf++)
        kf[t][hf] = *(const bf16x8*)(kb + ((2 * kh + t) * 2 + hf) * 512);
    const bf16_t* vb = VfB + (size_t)it * 4096;
#pragma unroll
    for (int ni = 0; ni < 4; ni++)
      vf[ni] = *(const bf16x8*)(vb + (kh * 4 + ni) * 512);
  };

  bf16x8 qf[4][2];
#pragma unroll
  for (int mi = 0; mi < 4; mi++) {
    const bf16_t* qr = Qp + (size_t)(64 * qh + mi * 16 + l15) * DK + quad * 8;
    qf[mi][0] = *(const bf16x8*)qr;
    qf[mi][1] = *(const bf16x8*)(qr + 32);
  }

  f32x4 accO[4][4], accS[4];
  const f32x4 z4 = {0.f, 0.f, 0.f, 0.f};
#pragma unroll
  for (int mi = 0; mi < 4; mi++) {
    accS[mi] = z4;
#pragma unroll
    for (int ni = 0; ni < 4; ni++) accO[mi][ni] = z4;
  }
  const bf16_t one = (bf16_t)1.0f;
  const bf16x8 ones = {one, one, one, one, one, one, one, one};

  const int wb0 = 32 * kh + 8 * quad - 64 * qh - l15 - it0 + 256;

  auto body = [&](int it, bf16x8 (&kf)[2][2], bf16x8 (&vf)[4]) {
    const int diff = it * 64 - it0;
    const bool band = (diff >= -128) && (diff < 256);
    const float cconst = diff >= 256 ? Bpos : Bneg;
    const f32x4 csplat = {cconst, cconst, cconst, cconst};
    const int jb = it * 64 + wb0;
#pragma unroll
    for (int mi = 0; mi < 4; mi++) {
      f32x4 c0, c1;
      if (band) {
        const int w = jb - mi * 16;
        float2 a0 = *(const float2*)bias2[w],     b0 = *(const float2*)bias2[w + 2];
        float2 a1 = *(const float2*)bias2[w + 4], b1 = *(const float2*)bias2[w + 6];
        c0 = f32x4{a0.x, a0.y, b0.x, b0.y};
        c1 = f32x4{a1.x, a1.y, b1.x, b1.y};
      } else {
        c0 = csplat;
        c1 = csplat;
      }
      f32x4 s0 = __builtin_amdgcn_mfma_f32_16x16x32_bf16(
          kf[0][1], qf[mi][1],
          __builtin_amdgcn_mfma_f32_16x16x32_bf16(kf[0][0], qf[mi][0], c0, 0, 0, 0), 0, 0, 0);
      f32x4 s1 = __builtin_amdgcn_mfma_f32_16x16x32_bf16(
          kf[1][1], qf[mi][1],
          __builtin_amdgcn_mfma_f32_16x16x32_bf16(kf[1][0], qf[mi][0], c1, 0, 0, 0), 0, 0, 0);
      bf16x8 pf = {(bf16_t)__builtin_amdgcn_exp2f(s0[0]), (bf16_t)__builtin_amdgcn_exp2f(s0[1]),
                   (bf16_t)__builtin_amdgcn_exp2f(s0[2]), (bf16_t)__builtin_amdgcn_exp2f(s0[3]),
                   (bf16_t)__builtin_amdgcn_exp2f(s1[0]), (bf16_t)__builtin_amdgcn_exp2f(s1[1]),
                   (bf16_t)__builtin_amdgcn_exp2f(s1[2]), (bf16_t)__builtin_amdgcn_exp2f(s1[3])};
#pragma unroll
      for (int ni = 0; ni < 4; ni++)
        accO[mi][ni] = __builtin_amdgcn_mfma_f32_16x16x32_bf16(vf[ni], pf, accO[mi][ni], 0, 0, 0);
      accS[mi] = __builtin_amdgcn_mfma_f32_16x16x32_bf16(ones, pf, accS[mi], 0, 0, 0);
    }
  };

  bf16x8 kf[2][2], vf[4];
  loadfrag(0, kf, vf);
  __syncthreads();  // bias2 ready

  for (int it = 0; it < 31; ++it) {
    body(it, kf, vf);
    loadfrag(it + 1, kf, vf);   // single buffer: issue after consumption; next body's
                                // vmcnt wait is covered by the other 2 waves per SIMD
  }
  body(31, kf, vf);

  __syncthreads();
  if (kh) {
#pragma unroll
    for (int mi = 0; mi < 4; mi++) {
#pragma unroll
      for (int ni = 0; ni < 4; ni++)
        Ored[((qh * 4 + mi) * 4 + ni) * 64 + lane] = accO[mi][ni];
      if (quad == 0) OsumS[qh][mi][l15] = accS[mi][0];
    }
  }
  __syncthreads();
  if (!kh) {
#pragma unroll
    for (int mi = 0; mi < 4; mi++) {
      float l = accS[mi][0] + OsumS[qh][mi][l15];
      float inv = 1.0f / l;
      int srow = it0 + 64 * qh + mi * 16 + l15;
#pragma unroll
      for (int ni = 0; ni < 4; ni++) {
        f32x4 o = accO[mi][ni] + Ored[((qh * 4 + mi) * 4 + ni) * 64 + lane];
        bf16x4 pk = {(bf16_t)(o[0] * inv), (bf16_t)(o[1] * inv),
                     (bf16_t)(o[2] * inv), (bf16_t)(o[3] * inv)};
        *(bf16x4*)(&ctx[((size_t)(b * SS + srow)) * DM + h * DK + ni * 16 + quad * 4]) = pk;
      }
    }
  }
}

// ---------------- output projection: out = ctx @ Wo (fp32 out), m-panel-fastest grid ------
__global__ __launch_bounds__(256) void k_gemm_out(const bf16_t* __restrict__ A,
                                                  const bf16_t* __restrict__ Wot,
                                                  float* __restrict__ out) {
  __shared__ bf16_t As[128 * 32];
  __shared__ bf16_t Bs[128 * 32];
  const int m0 = blockIdx.x * 128, n0 = blockIdx.y * 128;
  f32x4 acc[4][4];
  gemm_tile(A, Wot, DM, m0, n0, As, Bs, acc);

  const int tid = threadIdx.x;
  const int lane = tid & 63, wave = tid >> 6;
  const int l15 = lane & 15, quad = lane >> 4;
  const int wm = (wave >> 1) * 64, wn = (wave & 1) * 64;
#pragma unroll
  for (int i = 0; i < 4; i++)
#pragma unroll
    for (int j = 0; j < 4; j++)
#pragma unroll
      for (int r = 0; r < 4; r++) {
        int m = m0 + wm + i * 16 + quad * 4 + r;
        int n = n0 + wn + j * 16 + l15;
        out[(size_t)m * DM + n] = acc[i][j][r];
      }
}

extern "C" void kernel_launch(void* const* d_in, const int* in_sizes, int n_in,
                              void* d_out, int out_size, void* d_ws, size_t ws_size,
                              hipStream_t stream) {
  (void)in_sizes; (void)n_in; (void)out_size; (void)ws_size;
  const float* H  = (const float*)d_in[0];
  const float* Wq = (const float*)d_in[1];
  const float* Wk = (const float*)d_in[2];
  const float* Wv = (const float*)d_in[3];
  const float* Wo = (const float*)d_in[4];
  const float* rel = (const float*)d_in[5];
  float* out = (float*)d_out;

  char* w = (char*)d_ws;
  bf16_t* Hbf = (bf16_t*)w; w += (size_t)MM * DM * 2;
  bf16_t* Wqt = (bf16_t*)w; w += (size_t)DM * DM * 2;
  bf16_t* Wkt = (bf16_t*)w; w += (size_t)DM * DM * 2;
  bf16_t* Wvt = (bf16_t*)w; w += (size_t)DM * DM * 2;
  bf16_t* Wot = (bf16_t*)w; w += (size_t)DM * DM * 2;
  bf16_t* Q   = (bf16_t*)w; w += (size_t)MM * DM * 2;
  bf16_t* Kf  = (bf16_t*)w; w += (size_t)MM * DM * 2;
  bf16_t* Vf  = (bf16_t*)w; w += (size_t)MM * DM * 2;
  bf16_t* CTX = (bf16_t*)w; w += (size_t)MM * DM * 2;
  float* biasT = (float*)w;  // NH * 4095 floats

  k_prep<<<9232, 256, 0, stream>>>(H, Hbf, Wq, Wk, Wv, Wo, Wqt, Wkt, Wvt, Wot, rel, biasT);
  k_gemm_qkv<<<dim3(MM / 128, DM / 128, 3), 256, 0, stream>>>(Hbf, Wqt, Wkt, Wvt, Q, Kf, Vf);
  k_attn<<<dim3(SS / 128, NB * NH), 256, 0, stream>>>(Q, Kf, Vf, biasT, CTX);
  k_gemm_out<<<dim3(MM / 128, DM / 128), 256, 0, stream>>>(CTX, Wot, out);
}

// Round 3
// 259.226 us; speedup vs baseline: 1.0303x; 1.0275x over previous
//
#include <hip/hip_runtime.h>

typedef __bf16 bf16_t;
typedef __bf16 bf16x4 __attribute__((ext_vector_type(4)));
typedef __bf16 bf16x8 __attribute__((ext_vector_type(8)));
typedef float f32x4 __attribute__((ext_vector_type(4)));

#define NB 4        // batch
#define SS 2048     // seq
#define DM 1024     // d_model
#define NH 16       // heads
#define DK 64       // d_kv
#define MM (NB*SS)  // 8192 rows
#define LOG2E 1.44269504f

// ---------------- fused prep: convert H, transpose weights, bias table ----------------
__global__ __launch_bounds__(256) void k_prep(
    const float* __restrict__ H, bf16_t* __restrict__ Hbf,
    const float* __restrict__ W0, const float* __restrict__ W1,
    const float* __restrict__ W2, const float* __restrict__ W3,
    bf16_t* __restrict__ T0, bf16_t* __restrict__ T1,
    bf16_t* __restrict__ T2, bf16_t* __restrict__ T3,
    const float* __restrict__ rel_emb, float* __restrict__ biasT) {
  __shared__ float t[64][65];
  const int blk = blockIdx.x, tid = threadIdx.x;
  if (blk < 8192) {
    int i = blk * 256 + tid;
    float4 v = ((const float4*)H)[i];
    bf16x4 o = {(bf16_t)v.x, (bf16_t)v.y, (bf16_t)v.z, (bf16_t)v.w};
    *(bf16x4*)(Hbf + 4 * (size_t)i) = o;
  } else if (blk < 9216) {
    int tt = blk - 8192;
    int which = tt >> 8, rem = tt & 255;
    int k0 = (rem >> 4) * 64, n0 = (rem & 15) * 64;
    const float* W = which == 0 ? W0 : which == 1 ? W1 : which == 2 ? W2 : W3;
    bf16_t* T = which == 0 ? T0 : which == 1 ? T1 : which == 2 ? T2 : T3;
#pragma unroll
    for (int i = 0; i < 16; i++) {
      int idx = tid + i * 256; int r = idx >> 6, c = idx & 63;
      t[r][c] = W[(size_t)(k0 + r) * DM + n0 + c];
    }
    __syncthreads();
#pragma unroll
    for (int i = 0; i < 16; i++) {
      int idx = tid + i * 256; int r = idx >> 6, c = idx & 63;
      T[(size_t)(n0 + r) * DM + k0 + c] = (bf16_t)t[c][r];
    }
  } else {
    int tt = (blk - 9216) * 256 + tid;
    if (tt < 2 * SS - 1) {
      int rel = tt - (SS - 1);     // rel = j - i
      int n = -rel;
      int ret = 0;
      if (n < 0) { ret = 16; n = -n; }
      int bucket;
      if (n < 8) bucket = n;
      else {
        int v = 8 + (int)(logf((float)n * 0.125f) * (8.0f / logf(16.0f)));
        bucket = v < 15 ? v : 15;
      }
      bucket += ret;
#pragma unroll
      for (int h = 0; h < NH; h++)
        biasT[h * (2 * SS - 1) + tt] = rel_emb[bucket * NH + h] * LOG2E;
    }
  }
}

// ---------------- async 16B global -> LDS (lane i deposits at lds_base + 16*i) -------------
__device__ __forceinline__ void gld16(const bf16_t* g, bf16_t* l) {
  __builtin_amdgcn_global_load_lds(
      (const __attribute__((address_space(1))) unsigned int*)g,
      (__attribute__((address_space(3))) unsigned int*)l, 16, 0, 0);
}

// ---------------- m97-style GEMM mainloop: C[128x128] = A[MxK] * Bt[NxK]^T ----------------
__device__ __forceinline__ void gemm_tile(const bf16_t* __restrict__ A,
                                          const bf16_t* __restrict__ Bt, const int K,
                                          const int m0, const int n0,
                                          bf16_t* As, bf16_t* Bs, f32x4 (&acc)[4][4]) {
  const int tid = threadIdx.x;
  const int lane = tid & 63, wave = tid >> 6;
  const int l15 = lane & 15, quad = lane >> 4;
  const int wm = (wave >> 1) * 64, wn = (wave & 1) * 64;
  const int wwu = __builtin_amdgcn_readfirstlane(wave);
  const f32x4 z4 = {0.f, 0.f, 0.f, 0.f};
#pragma unroll
  for (int i = 0; i < 4; i++)
#pragma unroll
    for (int j = 0; j < 4; j++) acc[i][j] = z4;

  const int rr = lane >> 2;
  const int cc = (lane & 3) * 8;
  for (int k0 = 0; k0 < K; k0 += 32) {
    __syncthreads();
    gld16(A + (size_t)(m0 + wwu * 32 + rr) * K + k0 + cc,       As + wwu * 1024);
    gld16(A + (size_t)(m0 + wwu * 32 + 16 + rr) * K + k0 + cc,  As + wwu * 1024 + 512);
    gld16(Bt + (size_t)(n0 + wwu * 32 + rr) * K + k0 + cc,      Bs + wwu * 1024);
    gld16(Bt + (size_t)(n0 + wwu * 32 + 16 + rr) * K + k0 + cc, Bs + wwu * 1024 + 512);
    __syncthreads();
    bf16x8 af[4], bfr[4];
#pragma unroll
    for (int i = 0; i < 4; i++) {
      af[i]  = *(const bf16x8*)(As + (wm + i * 16 + l15) * 32 + quad * 8);
      bfr[i] = *(const bf16x8*)(Bs + (wn + i * 16 + l15) * 32 + quad * 8);
    }
#pragma unroll
    for (int i = 0; i < 4; i++)
#pragma unroll
      for (int j = 0; j < 4; j++)
        acc[i][j] = __builtin_amdgcn_mfma_f32_16x16x32_bf16(af[i], bfr[j], acc[i][j], 0, 0, 0);
  }
}

// ---------------- QKV projection (unchanged) ----------------
__global__ __launch_bounds__(256) void k_gemm_qkv(
    const bf16_t* __restrict__ A, const bf16_t* __restrict__ Wqt,
    const bf16_t* __restrict__ Wkt, const bf16_t* __restrict__ Wvt,
    bf16_t* __restrict__ Q, bf16_t* __restrict__ Kf, bf16_t* __restrict__ Vf) {
  __shared__ bf16_t As[128 * 32];
  __shared__ bf16_t Bs[128 * 32];
  const int which = blockIdx.z;
  const bf16_t* Bt = which == 0 ? Wqt : (which == 1 ? Wkt : Wvt);
  const int m0 = blockIdx.x * 128, n0 = blockIdx.y * 128;
  f32x4 acc[4][4];
  gemm_tile(A, Bt, DM, m0, n0, As, Bs, acc);

  const int tid = threadIdx.x;
  const int lane = tid & 63, wave = tid >> 6;
  const int l15 = lane & 15, quad = lane >> 4;
  const int wm = (wave >> 1) * 64, wn = (wave & 1) * 64;

  if (which == 0) {
#pragma unroll
    for (int i = 0; i < 4; i++)
#pragma unroll
      for (int j = 0; j < 4; j++)
#pragma unroll
        for (int r = 0; r < 4; r++) {
          int m = m0 + wm + i * 16 + quad * 4 + r;
          int n = n0 + wn + j * 16 + l15;
          int b = m >> 11, s = m & (SS - 1);
          int h = n >> 6, d = n & 63;
          Q[(((size_t)(b * NH + h)) * SS + s) * DK + d] = (bf16_t)(acc[i][j][r] * LOG2E);
        }
  } else if (which == 1) {
#pragma unroll
    for (int i = 0; i < 4; i++)
#pragma unroll
      for (int j = 0; j < 4; j++)
#pragma unroll
        for (int r = 0; r < 4; r++) {
          int m = m0 + wm + i * 16 + quad * 4 + r;
          int n = n0 + wn + j * 16 + l15;
          int b = m >> 11, s = m & (SS - 1);
          int h = n >> 6, d = n & 63;
          int slot = 4 * ((s >> 5) & 1) + 2 * ((s >> 2) & 1) + (d >> 5);
          int fl = ((d >> 3) & 3) * 16 + 4 * ((s >> 3) & 3) + (s & 3);
          Kf[(((size_t)(b * NH + h) * 32 + (s >> 6)) * 8 + slot) * 512 + fl * 8 + (d & 7)] =
              (bf16_t)acc[i][j][r];
        }
  } else {
#pragma unroll
    for (int i = 0; i < 4; i++)
#pragma unroll
      for (int j = 0; j < 4; j++) {
        int m = m0 + wm + i * 16 + quad * 4;   // 4 consecutive s, 4-aligned
        int n = n0 + wn + j * 16 + l15;
        int b = m >> 11, s = m & (SS - 1);
        int h = n >> 6, d = n & 63;
        int slot = 4 * ((s >> 5) & 1) + (d >> 4);
        int fl = ((s >> 3) & 3) * 16 + (d & 15);
        bf16x4 pk = {(bf16_t)acc[i][j][0], (bf16_t)acc[i][j][1],
                     (bf16_t)acc[i][j][2], (bf16_t)acc[i][j][3]};
        *(bf16x4*)(&Vf[(((size_t)(b * NH + h) * 32 + (s >> 6)) * 8 + slot) * 512 +
                       fl * 8 + (s & 7)]) = pk;
      }
  }
}

// ---------------- flash attention v4: R0 dbuf structure + XCD swizzle + T15 pipeline ------
// Post-mortem R1/R2: kernel is dependency-latency-bound. Traffic (swizzle: FETCH 140->28MB)
// and occupancy (18->24%) both moved with ZERO effect on time; the per-mi serial chain
// QK-mfma -> exp2 -> PV-mfma leaves both pipes at ~40%. Fix (T15, m214v36): shift PV one
// tile back. Per iteration the wave issues QK(it), then PV(it-1) (independent -> fills QK
// latency), then exp2(it) (overlaps next QK). Double-buffered loads split: loadK before the
// step (kf(it-1) dead), loadV after (vf(it-1) consumed by the PV inside) -> >=1 full step
// of slack per load. ~240 regs -> 2 waves/SIMD.
__global__ __launch_bounds__(256, 2) void k_attn(const bf16_t* __restrict__ Qg,
                                                 const bf16_t* __restrict__ Kf,
                                                 const bf16_t* __restrict__ Vf,
                                                 const float* __restrict__ biasT,
                                                 bf16_t* __restrict__ ctx) {
  const int lin = blockIdx.x + 16 * blockIdx.y;      // 1024 blocks, x fastest
  const int nid = (lin & 7) * 128 + (lin >> 3);      // bijective XCD chunking
  const int bh = nid >> 4;
  const int it0 = (nid & 15) * 128;
  const int b = bh >> 4, h = bh & 15;
  const bf16_t* Qp = Qg + ((size_t)bh * SS + it0) * DK;
  const float* biasH = biasT + h * (2 * SS - 1);

  __shared__ float bias2[512][2];         // diag-band: bias2[w] = {B(w-256), B(w-255)}
  __shared__ float OsumS[2][4][16];       // per (qh, mi, qrow) partial denominators
  __shared__ f32x4 Ored[2 * 4 * 4 * 64];  // 32 KB cross-wave O partials

  const int tid = threadIdx.x;
  const int lane = tid & 63, wave = tid >> 6;
  const int l15 = lane & 15, quad = lane >> 4;
  const int kh = wave & 1, qh = wave >> 1;

  for (int w = tid; w < 512; w += 256) {
    int g = w - 256 + (SS - 1);
    bias2[w][0] = biasH[g];
    bias2[w][1] = biasH[g + 1];
  }
  const float Bpos = biasH[(SS - 1) + 1024];   // rel >= 128: saturated bucket 31
  const float Bneg = biasH[(SS - 1) - 1024];   // rel <= -128: saturated bucket 15

  const bf16_t* KfB = Kf + (size_t)bh * 32 * 4096 + lane * 8;
  const bf16_t* VfB = Vf + (size_t)bh * 32 * 4096 + lane * 8;
  auto loadK = [&](int it, bf16x8 (&kf)[2][2]) {
    const bf16_t* kb = KfB + (size_t)it * 4096;
#pragma unroll
    for (int t = 0; t < 2; t++)
#pragma unroll
      for (int hf = 0; hf < 2; hf++)
        kf[t][hf] = *(const bf16x8*)(kb + ((2 * kh + t) * 2 + hf) * 512);
  };
  auto loadV = [&](int it, bf16x8 (&vf)[4]) {
    const bf16_t* vb = VfB + (size_t)it * 4096;
#pragma unroll
    for (int ni = 0; ni < 4; ni++)
      vf[ni] = *(const bf16x8*)(vb + (kh * 4 + ni) * 512);
  };

  bf16x8 qf[4][2];
#pragma unroll
  for (int mi = 0; mi < 4; mi++) {
    const bf16_t* qr = Qp + (size_t)(64 * qh + mi * 16 + l15) * DK + quad * 8;
    qf[mi][0] = *(const bf16x8*)qr;
    qf[mi][1] = *(const bf16x8*)(qr + 32);
  }

  f32x4 accO[4][4], accS[4];
  const f32x4 z4 = {0.f, 0.f, 0.f, 0.f};
#pragma unroll
  for (int mi = 0; mi < 4; mi++) {
    accS[mi] = z4;
#pragma unroll
    for (int ni = 0; ni < 4; ni++) accO[mi][ni] = z4;
  }
  const bf16_t one = (bf16_t)1.0f;
  const bf16x8 ones = {one, one, one, one, one, one, one, one};

  const int wb0 = 32 * kh + 8 * quad - 64 * qh - l15 - it0 + 256;

  // QK(it) + exp2 -> pfC; PV(it-1) from pfP/vfP interleaved per-mi (fills QK latency).
  auto step = [&](int it, bf16x8 (&kfC)[2][2], bf16x8 (&pfP)[4], bf16x8 (&vfP)[4],
                  bf16x8 (&pfC)[4]) {
    const int diff = it * 64 - it0;
    const bool band = (diff >= -128) && (diff < 256);
    const float cconst = diff >= 256 ? Bpos : Bneg;
    const f32x4 csplat = {cconst, cconst, cconst, cconst};
    const int jb = it * 64 + wb0;
#pragma unroll
    for (int mi = 0; mi < 4; mi++) {
      f32x4 c0, c1;
      if (band) {
        const int w = jb - mi * 16;
        float2 a0 = *(const float2*)bias2[w],     b0 = *(const float2*)bias2[w + 2];
        float2 a1 = *(const float2*)bias2[w + 4], b1 = *(const float2*)bias2[w + 6];
        c0 = f32x4{a0.x, a0.y, b0.x, b0.y};
        c1 = f32x4{a1.x, a1.y, b1.x, b1.y};
      } else {
        c0 = csplat;
        c1 = csplat;
      }
      f32x4 s0 = __builtin_amdgcn_mfma_f32_16x16x32_bf16(
          kfC[0][1], qf[mi][1],
          __builtin_amdgcn_mfma_f32_16x16x32_bf16(kfC[0][0], qf[mi][0], c0, 0, 0, 0), 0, 0, 0);
      f32x4 s1 = __builtin_amdgcn_mfma_f32_16x16x32_bf16(
          kfC[1][1], qf[mi][1],
          __builtin_amdgcn_mfma_f32_16x16x32_bf16(kfC[1][0], qf[mi][0], c1, 0, 0, 0), 0, 0, 0);
      // PV of previous tile, same mi: independent of s0/s1 -> scheduler fills QK latency
#pragma unroll
      for (int ni = 0; ni < 4; ni++)
        accO[mi][ni] =
            __builtin_amdgcn_mfma_f32_16x16x32_bf16(vfP[ni], pfP[mi], accO[mi][ni], 0, 0, 0);
      accS[mi] = __builtin_amdgcn_mfma_f32_16x16x32_bf16(ones, pfP[mi], accS[mi], 0, 0, 0);
      pfC[mi] =
          bf16x8{(bf16_t)__builtin_amdgcn_exp2f(s0[0]), (bf16_t)__builtin_amdgcn_exp2f(s0[1]),
                 (bf16_t)__builtin_amdgcn_exp2f(s0[2]), (bf16_t)__builtin_amdgcn_exp2f(s0[3]),
                 (bf16_t)__builtin_amdgcn_exp2f(s1[0]), (bf16_t)__builtin_amdgcn_exp2f(s1[1]),
                 (bf16_t)__builtin_amdgcn_exp2f(s1[2]), (bf16_t)__builtin_amdgcn_exp2f(s1[3])};
    }
  };
  // tile 0: QK + exp only (no previous tile)
  auto step0 = [&](bf16x8 (&kfC)[2][2], bf16x8 (&pfC)[4]) {
    const int diff = -it0;
    const bool band = (diff >= -128) && (diff < 256);
    const float cconst = diff >= 256 ? Bpos : Bneg;
    const f32x4 csplat = {cconst, cconst, cconst, cconst};
    const int jb = wb0;
#pragma unroll
    for (int mi = 0; mi < 4; mi++) {
      f32x4 c0, c1;
      if (band) {
        const int w = jb - mi * 16;
        float2 a0 = *(const float2*)bias2[w],     b0 = *(const float2*)bias2[w + 2];
        float2 a1 = *(const float2*)bias2[w + 4], b1 = *(const float2*)bias2[w + 6];
        c0 = f32x4{a0.x, a0.y, b0.x, b0.y};
        c1 = f32x4{a1.x, a1.y, b1.x, b1.y};
      } else {
        c0 = csplat;
        c1 = csplat;
      }
      f32x4 s0 = __builtin_amdgcn_mfma_f32_16x16x32_bf16(
          kfC[0][1], qf[mi][1],
          __builtin_amdgcn_mfma_f32_16x16x32_bf16(kfC[0][0], qf[mi][0], c0, 0, 0, 0), 0, 0, 0);
      f32x4 s1 = __builtin_amdgcn_mfma_f32_16x16x32_bf16(
          kfC[1][1], qf[mi][1],
          __builtin_amdgcn_mfma_f32_16x16x32_bf16(kfC[1][0], qf[mi][0], c1, 0, 0, 0), 0, 0, 0);
      pfC[mi] =
          bf16x8{(bf16_t)__builtin_amdgcn_exp2f(s0[0]), (bf16_t)__builtin_amdgcn_exp2f(s0[1]),
                 (bf16_t)__builtin_amdgcn_exp2f(s0[2]), (bf16_t)__builtin_amdgcn_exp2f(s0[3]),
                 (bf16_t)__builtin_amdgcn_exp2f(s1[0]), (bf16_t)__builtin_amdgcn_exp2f(s1[1]),
                 (bf16_t)__builtin_amdgcn_exp2f(s1[2]), (bf16_t)__builtin_amdgcn_exp2f(s1[3])};
    }
  };

  bf16x8 kfA[2][2], vfA[4], kfB[2][2], vfB[4], pfA[4], pfB[4];
  loadK(0, kfA);
  loadV(0, vfA);
  __syncthreads();  // bias2 ready
  loadK(1, kfB);
  step0(kfA, pfA);      // QK(0) -> pfA
  loadV(1, vfB);

  for (int it = 1; it < 32; it += 2) {
    // odd it: cur = B buffers, prev = A
    if (it + 1 < 32) loadK(it + 1, kfA);   // kfA dead since QK(it-1)
    step(it, kfB, pfA, vfA, pfB);          // QK(it); PV(it-1) consumes vfA
    if (it + 1 < 32) {
      loadV(it + 1, vfA);                  // vfA dead now
      loadK(it + 2, kfB);                  // it+2 <= 31 whenever this branch runs
      step(it + 1, kfA, pfB, vfB, pfA);    // QK(it+1); PV(it) consumes vfB
      loadV(it + 2, vfB);
    }
  }
  // PV for the last tile (31): pfB produced by step(31), vfB holds vf(31)
#pragma unroll
  for (int mi = 0; mi < 4; mi++) {
#pragma unroll
    for (int ni = 0; ni < 4; ni++)
      accO[mi][ni] =
          __builtin_amdgcn_mfma_f32_16x16x32_bf16(vfB[ni], pfB[mi], accO[mi][ni], 0, 0, 0);
    accS[mi] = __builtin_amdgcn_mfma_f32_16x16x32_bf16(ones, pfB[mi], accS[mi], 0, 0, 0);
  }

  __syncthreads();
  if (kh) {
#pragma unroll
    for (int mi = 0; mi < 4; mi++) {
#pragma unroll
      for (int ni = 0; ni < 4; ni++)
        Ored[((qh * 4 + mi) * 4 + ni) * 64 + lane] = accO[mi][ni];
      if (quad == 0) OsumS[qh][mi][l15] = accS[mi][0];
    }
  }
  __syncthreads();
  if (!kh) {
#pragma unroll
    for (int mi = 0; mi < 4; mi++) {
      float l = accS[mi][0] + OsumS[qh][mi][l15];
      float inv = 1.0f / l;
      int srow = it0 + 64 * qh + mi * 16 + l15;
#pragma unroll
      for (int ni = 0; ni < 4; ni++) {
        f32x4 o = accO[mi][ni] + Ored[((qh * 4 + mi) * 4 + ni) * 64 + lane];
        bf16x4 pk = {(bf16_t)(o[0] * inv), (bf16_t)(o[1] * inv),
                     (bf16_t)(o[2] * inv), (bf16_t)(o[3] * inv)};
        *(bf16x4*)(&ctx[((size_t)(b * SS + srow)) * DM + h * DK + ni * 16 + quad * 4]) = pk;
      }
    }
  }
}

// ---------------- output projection: out = ctx @ Wo (fp32 out), m-panel-fastest grid ------
__global__ __launch_bounds__(256) void k_gemm_out(const bf16_t* __restrict__ A,
                                                  const bf16_t* __restrict__ Wot,
                                                  float* __restrict__ out) {
  __shared__ bf16_t As[128 * 32];
  __shared__ bf16_t Bs[128 * 32];
  const int m0 = blockIdx.x * 128, n0 = blockIdx.y * 128;
  f32x4 acc[4][4];
  gemm_tile(A, Wot, DM, m0, n0, As, Bs, acc);

  const int tid = threadIdx.x;
  const int lane = tid & 63, wave = tid >> 6;
  const int l15 = lane & 15, quad = lane >> 4;
  const int wm = (wave >> 1) * 64, wn = (wave & 1) * 64;
#pragma unroll
  for (int i = 0; i < 4; i++)
#pragma unroll
    for (int j = 0; j < 4; j++)
#pragma unroll
      for (int r = 0; r < 4; r++) {
        int m = m0 + wm + i * 16 + quad * 4 + r;
        int n = n0 + wn + j * 16 + l15;
        out[(size_t)m * DM + n] = acc[i][j][r];
      }
}

extern "C" void kernel_launch(void* const* d_in, const int* in_sizes, int n_in,
                              void* d_out, int out_size, void* d_ws, size_t ws_size,
                              hipStream_t stream) {
  (void)in_sizes; (void)n_in; (void)out_size; (void)ws_size;
  const float* H  = (const float*)d_in[0];
  const float* Wq = (const float*)d_in[1];
  const float* Wk = (const float*)d_in[2];
  const float* Wv = (const float*)d_in[3];
  const float* Wo = (const float*)d_in[4];
  const float* rel = (const float*)d_in[5];
  float* out = (float*)d_out;

  char* w = (char*)d_ws;
  bf16_t* Hbf = (bf16_t*)w; w += (size_t)MM * DM * 2;
  bf16_t* Wqt = (bf16_t*)w; w += (size_t)DM * DM * 2;
  bf16_t* Wkt = (bf16_t*)w; w += (size_t)DM * DM * 2;
  bf16_t* Wvt = (bf16_t*)w; w += (size_t)DM * DM * 2;
  bf16_t* Wot = (bf16_t*)w; w += (size_t)DM * DM * 2;
  bf16_t* Q   = (bf16_t*)w; w += (size_t)MM * DM * 2;
  bf16_t* Kf  = (bf16_t*)w; w += (size_t)MM * DM * 2;
  bf16_t* Vf  = (bf16_t*)w; w += (size_t)MM * DM * 2;
  bf16_t* CTX = (bf16_t*)w; w += (size_t)MM * DM * 2;
  float* biasT = (float*)w;  // NH * 4095 floats

  k_prep<<<9232, 256, 0, stream>>>(H, Hbf, Wq, Wk, Wv, Wo, Wqt, Wkt, Wvt, Wot, rel, biasT);
  k_gemm_qkv<<<dim3(MM / 128, DM / 128, 3), 256, 0, stream>>>(Hbf, Wqt, Wkt, Wvt, Q, Kf, Vf);
  k_attn<<<dim3(SS / 128, NB * NH), 256, 0, stream>>>(Q, Kf, Vf, biasT, CTX);
  k_gemm_out<<<dim3(MM / 128, DM / 128), 256, 0, stream>>>(CTX, Wot, out);
}